// Round 3
// baseline (232.513 us; speedup 1.0000x reference)
//
#include <hip/hip_runtime.h>
#include <hip/hip_bf16.h>

#define A_TOTAL 110484
#define NCLS 80
#define CAP 4096
#define MAX_DETS 100
#define IMGF 768.0f
#define IOU_T 0.2f

struct Ws {
    int count;
    int pad[3];
    float score[CAP];
    int anchor[CAP];
    int label[CAP];
    float4 box[CAP];
};

// Phase 1: per-anchor max/argmax over 80 classes, sigmoid+threshold, decode+clip,
// atomic compaction of candidates into workspace.
__global__ void score_decode_kernel(const float* __restrict__ cls,
                                    const float* __restrict__ reg,
                                    const float* __restrict__ anc,
                                    Ws* __restrict__ ws) {
    int a = blockIdx.x * blockDim.x + threadIdx.x;
    if (a >= A_TOTAL) return;

    const float4* row = (const float4*)(cls + (size_t)a * NCLS);
    float m = -1e30f;
    int lbl = 0;
#pragma unroll
    for (int i = 0; i < NCLS / 4; ++i) {
        float4 v = row[i];
        if (v.x > m) { m = v.x; lbl = i * 4 + 0; }
        if (v.y > m) { m = v.y; lbl = i * 4 + 1; }
        if (v.z > m) { m = v.z; lbl = i * 4 + 2; }
        if (v.w > m) { m = v.w; lbl = i * 4 + 3; }
    }

    float sig = 1.0f / (1.0f + expf(-m));
    if (!(sig > 0.2f)) return;

    // decode (avoid FMA contraction: match numpy's separate mul/add roundings)
    float4 ab = ((const float4*)anc)[a];  // y1,x1,y2,x2
    float4 rb = ((const float4*)reg)[a];  // dy,dx,dh,dw
    float ya = __fmul_rn(__fadd_rn(ab.x, ab.z), 0.5f);
    float xa = __fmul_rn(__fadd_rn(ab.y, ab.w), 0.5f);
    float ha = __fsub_rn(ab.z, ab.x);
    float wa = __fsub_rn(ab.w, ab.y);
    float w = __fmul_rn(expf(rb.w), wa);
    float h = __fmul_rn(expf(rb.z), ha);
    float yc = __fadd_rn(__fmul_rn(rb.x, ha), ya);
    float xc = __fadd_rn(__fmul_rn(rb.y, wa), xa);
    float x1 = fmaxf(__fsub_rn(xc, __fmul_rn(w, 0.5f)), 0.0f);
    float y1 = fmaxf(__fsub_rn(yc, __fmul_rn(h, 0.5f)), 0.0f);
    float x2 = fminf(__fadd_rn(xc, __fmul_rn(w, 0.5f)), IMGF);
    float y2 = fminf(__fadd_rn(yc, __fmul_rn(h, 0.5f)), IMGF);

    int pos = atomicAdd(&ws->count, 1);
    if (pos < CAP) {
        ws->score[pos] = sig;
        ws->anchor[pos] = a;
        ws->label[pos] = lbl;
        ws->box[pos] = make_float4(x1, y1, x2, y2);
    }
}

// Phase 2: single-block sort (bitonic, key = (~score_bits)<<32 | anchor -> exact
// argsort(-scores) order) + greedy NMS + output write.
__global__ __launch_bounds__(1024, 1) void nms_kernel(const Ws* __restrict__ ws,
                                                      float* __restrict__ out) {
    __shared__ unsigned long long keys[CAP];
    __shared__ int payload[CAP];
    __shared__ float bx1[CAP], by1[CAP], bx2[CAP], by2[CAP], barea[CAP];
    __shared__ unsigned char act[CAP];
    __shared__ int keep_slot[MAX_DETS];
    __shared__ int s_j, s_n;

    int tid = threadIdx.x;
    int n = ws->count;
    if (n > CAP) n = CAP;

    for (int s = tid; s < CAP; s += 1024) {
        if (s < n) {
            unsigned int sb = __float_as_uint(ws->score[s]);
            keys[s] = ((unsigned long long)(~sb) << 32) | (unsigned int)ws->anchor[s];
            payload[s] = s;
        } else {
            keys[s] = 0xFFFFFFFFFFFFFFFFull;
            payload[s] = -1;
        }
    }
    __syncthreads();

    // bitonic sort ascending over CAP elements
    for (int k = 2; k <= CAP; k <<= 1) {
        for (int j = k >> 1; j > 0; j >>= 1) {
            for (int i = tid; i < CAP; i += 1024) {
                int ixj = i ^ j;
                if (ixj > i) {
                    bool up = ((i & k) == 0);
                    unsigned long long ka = keys[i], kb = keys[ixj];
                    if ((ka > kb) == up) {
                        keys[i] = kb; keys[ixj] = ka;
                        int p = payload[i]; payload[i] = payload[ixj]; payload[ixj] = p;
                    }
                }
            }
            __syncthreads();
        }
    }

    // stage sorted boxes + areas
    for (int s = tid; s < n; s += 1024) {
        int slot = payload[s];
        float4 b = ws->box[slot];
        bx1[s] = b.x; by1[s] = b.y; bx2[s] = b.z; by2[s] = b.w;
        barea[s] = __fmul_rn(__fsub_rn(b.z, b.x), __fsub_rn(b.w, b.y));
        act[s] = 1;
    }
    if (tid == 0) { s_j = -1; s_n = 0; }
    __syncthreads();

    // greedy NMS: next pick is always the first still-active sorted entry
    for (int it = 0; it < MAX_DETS; ++it) {
        if (tid == 0) {
            int start = (it == 0) ? 0 : s_j + 1;
            int j = -1;
            for (int s = start; s < n; ++s) {
                if (act[s]) { j = s; break; }
            }
            s_j = j;
            if (j >= 0) { keep_slot[s_n] = j; s_n = s_n + 1; }
        }
        __syncthreads();
        int j = s_j;
        if (j < 0) break;
        float cx1 = bx1[j], cy1 = by1[j], cx2 = bx2[j], cy2 = by2[j], ca = barea[j];
        for (int s = tid; s < n; s += 1024) {
            if (act[s]) {
                float ix1 = fmaxf(cx1, bx1[s]);
                float iy1 = fmaxf(cy1, by1[s]);
                float ix2 = fminf(cx2, bx2[s]);
                float iy2 = fminf(cy2, by2[s]);
                float iw = fmaxf(__fsub_rn(ix2, ix1), 0.0f);
                float ih = fmaxf(__fsub_rn(iy2, iy1), 0.0f);
                float inter = __fmul_rn(iw, ih);
                float denom = __fadd_rn(__fadd_rn(__fadd_rn(ca, barea[s]), -inter), 1e-8f);
                float iou = __fdiv_rn(inter, denom);
                if (!(iou < IOU_T)) act[s] = 0;
            }
        }
        __syncthreads();
    }
    __syncthreads();

    int nk = s_n;
    if (tid < MAX_DETS) {
        float b0 = 0.f, b1 = 0.f, b2 = 0.f, b3 = 0.f, sc = 0.f, lb = 0.f;
        if (tid < nk) {
            int s = keep_slot[tid];
            b0 = bx1[s]; b1 = by1[s]; b2 = bx2[s]; b3 = by2[s];
            unsigned int sb = ~(unsigned int)(keys[s] >> 32);
            sc = __uint_as_float(sb);
            lb = (float)ws->label[payload[s]];
        }
        out[tid * 4 + 0] = b0;
        out[tid * 4 + 1] = b1;
        out[tid * 4 + 2] = b2;
        out[tid * 4 + 3] = b3;
        out[400 + tid] = sc;
        out[500 + tid] = lb;
    }
}

extern "C" void kernel_launch(void* const* d_in, const int* in_sizes, int n_in,
                              void* d_out, int out_size, void* d_ws, size_t ws_size,
                              hipStream_t stream) {
    const float* reg = (const float*)d_in[1];
    const float* cls = (const float*)d_in[2];
    const float* anc = (const float*)d_in[3];
    Ws* ws = (Ws*)d_ws;

    hipMemsetAsync(d_ws, 0, sizeof(int), stream);  // zero candidate count

    int blocks = (A_TOTAL + 255) / 256;
    score_decode_kernel<<<blocks, 256, 0, stream>>>(cls, reg, anc, ws);
    nms_kernel<<<1, 1024, 0, stream>>>(ws, (float*)d_out);
}